// Round 8
// baseline (827.571 us; speedup 1.0000x reference)
//
#include <hip/hip_runtime.h>

#define T_TOKENS 2048
#define HIDDEN   2048
#define NEXPERT  32
#define TOPK     4
#define INTER    768
#define GUF      (2*INTER)         /* 1536 */
#define NPAIRS   (T_TOKENS*TOPK)   /* 8192 */
#define BM       128
#define BK       32
#define MT_MAX   95                /* sum ceil(cnt/128) <= 64 + 31 */
#define NT1      12                /* 768/64 fused gate+up col-tiles */
#define NT2      16                /* 2048/128 */
#define NK1      (HIDDEN/BK)       /* 64 */
#define NK2      (INTER/BK)        /* 24 */

typedef short  bh8 __attribute__((ext_vector_type(8)));   // 8 bf16
typedef float  fx4 __attribute__((ext_vector_type(4)));

#define AS1 __attribute__((address_space(1)))
#define AS3 __attribute__((address_space(3)))

__device__ __forceinline__ void gload_lds16(const void* g, const void* lds_generic){
    __builtin_amdgcn_global_load_lds(
        (const AS1 void*)(unsigned long long)g,
        (AS3 void*)(unsigned int)(unsigned long long)lds_generic,
        16, 0, 0);
}

__device__ __forceinline__ unsigned int pack2bf(float a, float b){
    unsigned ua = __float_as_uint(a) + 0x8000u;
    unsigned ub = __float_as_uint(b) + 0x8000u;
    return __builtin_amdgcn_perm(ub, ua, 0x07060302u);
}
__device__ __forceinline__ unsigned short f2bfu(float f){
    return (unsigned short)((__float_as_uint(f) + 0x8000u) >> 16);
}

/* ---------------- x -> bf16 ---------------- */
__global__ void cvt_x_k(const float* __restrict__ x, unsigned short* __restrict__ xb){
    int i = (blockIdx.x*256 + threadIdx.x)*8;
    float4 a = *(const float4*)(x+i);
    float4 b = *(const float4*)(x+i+4);
    uint4 o;
    o.x = pack2bf(a.x,a.y); o.y = pack2bf(a.z,a.w);
    o.z = pack2bf(b.x,b.y); o.w = pack2bf(b.z,b.w);
    *(uint4*)(xb+i) = o;
}

/* ---------------- router ---------------- */
__global__ void router_k(const float* __restrict__ x, const float* __restrict__ gate,
                         int* __restrict__ topk_id, float* __restrict__ topk_w,
                         int* __restrict__ counts){
    const int t = blockIdx.x;
    const int l = threadIdx.x;
    const float* xr = x + (size_t)t*HIDDEN;
    float acc[NEXPERT];
#pragma unroll
    for (int e=0;e<NEXPERT;e++) acc[e]=0.f;
    for (int d=l; d<HIDDEN; d+=64){
        float xv = xr[d];
        const float4* g4 = (const float4*)(gate + (size_t)d*NEXPERT);
#pragma unroll
        for (int i=0;i<8;i++){
            float4 g = g4[i];
            acc[i*4+0] += xv*g.x; acc[i*4+1] += xv*g.y;
            acc[i*4+2] += xv*g.z; acc[i*4+3] += xv*g.w;
        }
    }
#pragma unroll
    for (int e=0;e<NEXPERT;e++){
#pragma unroll
        for (int m=1;m<64;m<<=1) acc[e] += __shfl_xor(acc[e], m, 64);
    }
    int ids[TOPK]; float lv[TOPK];
#pragma unroll
    for (int k=0;k<TOPK;k++){
        float m=-1e30f; int mi=0;
#pragma unroll
        for (int e=0;e<NEXPERT;e++){ if (acc[e]>m){ m=acc[e]; mi=e; } }
        ids[k]=mi; lv[k]=m; acc[mi]=-1e30f;
    }
    float ex[TOPK]; float s=0.f;
#pragma unroll
    for (int k=0;k<TOPK;k++){ ex[k]=__expf(lv[k]-lv[0]); s+=ex[k]; }
    if (l==0){
        float inv = 1.f/s;
#pragma unroll
        for (int k=0;k<TOPK;k++){
            topk_id[t*TOPK+k]=ids[k];
            topk_w[t*TOPK+k]=ex[k]*inv;
            atomicAdd(&counts[ids[k]],1);
        }
    }
}

/* ---------------- schedule ---------------- */
__global__ void sched_k(const int* __restrict__ counts, int* __restrict__ offs,
                        int* __restrict__ cursors, int* __restrict__ nmt,
                        int* __restrict__ te, int* __restrict__ tr0, int* __restrict__ trn){
    if (threadIdx.x==0 && blockIdx.x==0){
        int tot=0, nm=0;
        for (int e=0;e<NEXPERT;e++){
            int c = counts[e];
            offs[e]=tot; cursors[e]=tot;
            for (int s=0;s<c;s+=BM){
                te[nm]=e; tr0[nm]=tot+s; trn[nm]=(c-s)<BM?(c-s):BM; nm++;
            }
            tot+=c;
        }
        *nmt = nm;
    }
}

/* ---------------- scatter ---------------- */
__global__ void scatter_k(const int* __restrict__ topk_id, const float* __restrict__ topk_w,
                          int* __restrict__ cursors, int* __restrict__ pair_tok,
                          float* __restrict__ pair_w){
    int g = blockIdx.x*256 + threadIdx.x;
    int e = topk_id[g];
    float w = topk_w[g];
    int pos = atomicAdd(&cursors[e],1);
    pair_tok[pos] = g>>2;
    pair_w[pos]  = w;
}

/* tile-id decode: bijective XCD-chunked swizzle, mt innermost */
#define TILE_DECODE()                                              \
    const int nwg = gridDim.x;                                     \
    const int q = nwg>>3, r = nwg&7;                               \
    const int xcd = blockIdx.x & 7, bidx = blockIdx.x >> 3;        \
    const int L = (xcd<r ? xcd*(q+1) : r*(q+1)+(xcd-r)*q) + bidx;  \
    const int mt = L % MT_MAX, nt = L / MT_MAX;                    \
    if (mt >= *nmt) return;                                        \
    const int e = te[mt], row0 = tr0[mt], rows = trn[mt];

#define MFMA16(A,B,C) __builtin_amdgcn_mfma_f32_16x16x32_bf16(A,B,C,0,0,0)

/* ============== grouped GEMM1 (template: V0 real, V1 noMFMA, V2 B@k0, V3 noA-DMA) ====
   512 thr = 8 waves; wr=w&1 (64-row grp), wc=w>>1 (16-col grp, c: 0=gate 1=up).  */
template<int V>
__global__ __launch_bounds__(512,6) void gemm1_t(
        const unsigned short* __restrict__ xb, const float* __restrict__ gup,
        const int* __restrict__ nmt, const int* __restrict__ te,
        const int* __restrict__ tr0, const int* __restrict__ trn,
        const int* __restrict__ pair_tok, const float* __restrict__ pair_w,
        unsigned short* __restrict__ gated){
    __shared__ __align__(16) unsigned short As[2][BM*32];   // 2 x 8KB linear rows
    __shared__ __align__(16) unsigned short Bs[2][BM*40];   // 2 x 10KB [col][k] pitch 80B
    __shared__ int   s_tok[BM];
    __shared__ float s_w[BM];

    TILE_DECODE()
    const int n0 = nt*64;

    const int t = threadIdx.x;
    if (t < BM){
        int p = row0 + t; if (p > NPAIRS-1) p = NPAIRS-1;
        s_tok[t] = pair_tok[p];
        s_w[t]   = pair_w[p];
    }
    __syncthreads();

    const int w = t>>6, lane = t&63;
    const int l15 = lane & 15, kb = lane >> 4;
    const int wr = w & 1, wc = w >> 1;
    const int sA = (l15>>1)&3;

    // A DMA: wave w stages rows w*16..+15
    const int arow = w*16 + (lane>>2);
    const int ck0 = (lane&3) ^ ((lane>>3)&3);
    const unsigned short* asrc = xb + (size_t)s_tok[arow]*HIDDEN + ck0*8;

    // B staging: thread -> 4 cols x 2 k-rows (f32->bf16 reg transpose)
    const int col4 = (t&31)*4;
    const int bd0  = (t>>5)*2;
    const unsigned wb = (unsigned)(col4*80 + (((bd0>>3) ^ ((col4>>3)&3))<<4) + (bd0&7)*2);
    const int fc = (col4 < 64) ? (n0 + col4) : (704 + n0 + col4);
    const float* bsrc = gup + (size_t)e*HIDDEN*GUF + (size_t)bd0*GUF + fc;

    fx4 acc[4][2];
#pragma unroll
    for (int i=0;i<4;i++){ acc[i][0]=(fx4)0.f; acc[i][1]=(fx4)0.f; }

    float4 rv0, rv1;
    int dk = 0;
#define LOADB1(KS) do{                                                          \
    const float* _bp = (V==2) ? bsrc : bsrc + (size_t)(KS)*BK*GUF;              \
    rv0 = *(const float4*)(_bp); rv1 = *(const float4*)(_bp + GUF); }while(0)
#define WRITEB1(BUF) do{ char* _bb = (char*)Bs[BUF];                            \
    *(unsigned*)(_bb + wb      ) = pack2bf(rv0.x, rv1.x);                       \
    *(unsigned*)(_bb + wb +  80) = pack2bf(rv0.y, rv1.y);                       \
    *(unsigned*)(_bb + wb + 160) = pack2bf(rv0.z, rv1.z);                       \
    *(unsigned*)(_bb + wb + 240) = pack2bf(rv0.w, rv1.w); }while(0)
#define STAGEA1(KS,BUF) gload_lds16(asrc + (KS)*BK, &As[BUF][(w*16)*32])
#define COMPUTE1(BUF) do{                                                       \
    const unsigned short* _Ak = As[BUF];                                        \
    const char* _Bb = (const char*)Bs[BUF];                                     \
    bh8 _a0 = *(const bh8*)(_Ak + (wr*64      + l15)*32 + ((kb^sA)<<3));        \
    bh8 _a1 = *(const bh8*)(_Ak + (wr*64 + 16 + l15)*32 + ((kb^sA)<<3));        \
    bh8 _a2 = *(const bh8*)(_Ak + (wr*64 + 32 + l15)*32 + ((kb^sA)<<3));        \
    bh8 _a3 = *(const bh8*)(_Ak + (wr*64 + 48 + l15)*32 + ((kb^sA)<<3));        \
    const int _bc0 = wc*16 + l15, _bc1 = 64 + wc*16 + l15;                      \
    bh8 _b0 = *(const bh8*)(_Bb + _bc0*80 + ((kb ^ ((_bc0>>3)&3))<<4));         \
    bh8 _b1 = *(const bh8*)(_Bb + _bc1*80 + ((kb ^ ((_bc1>>3)&3))<<4));         \
    if (V==1){                                                                  \
        dk ^= _a0[0]^_a1[0]^_a2[0]^_a3[0]^_b0[0]^_b1[0];                        \
    } else {                                                                    \
        acc[0][0]=MFMA16(_a0,_b0,acc[0][0]); acc[0][1]=MFMA16(_a0,_b1,acc[0][1]); \
        acc[1][0]=MFMA16(_a1,_b0,acc[1][0]); acc[1][1]=MFMA16(_a1,_b1,acc[1][1]); \
        acc[2][0]=MFMA16(_a2,_b0,acc[2][0]); acc[2][1]=MFMA16(_a2,_b1,acc[2][1]); \
        acc[3][0]=MFMA16(_a3,_b0,acc[3][0]); acc[3][1]=MFMA16(_a3,_b1,acc[3][1]); \
    } }while(0)

    // prologue
    STAGEA1(0,0);
    if (V==3) STAGEA1(1,1);
    LOADB1(0);
    __syncthreads();
    WRITEB1(0);
    __syncthreads();

    for (int k=0;k<NK1;k++){
        const int kn = k+1;
        if (kn < NK1){ LOADB1(kn); if (V!=3) STAGEA1(kn, kn&1); }
        COMPUTE1(k&1);
        __syncthreads();
        if (kn < NK1) WRITEB1(kn&1);
        __syncthreads();
    }
    if (V==1) asm volatile("" :: "v"(dk));

    // epilogue: gated = silu(g)*u*router_w
#pragma unroll
    for (int mr=0;mr<4;mr++){
#pragma unroll
        for (int qq=0;qq<4;qq++){
            int row = wr*64 + mr*16 + kb*4 + qq;
            if (row < rows){
                float wgt = s_w[row];
                float g = acc[mr][0][qq], u = acc[mr][1][qq];
                float sil = g / (1.f + __expf(-g));
                gated[(size_t)(row0 + row)*INTER + n0 + wc*16 + l15] = f2bfu(sil*u*wgt);
            }
        }
    }
#undef LOADB1
#undef WRITEB1
#undef STAGEA1
#undef COMPUTE1
}

/* ============== grouped GEMM2: gated(bf16) x down(f32) -> out (atomic f32) ============== */
__global__ __launch_bounds__(512,6) void gemm2_k(
        const unsigned short* __restrict__ gated, const float* __restrict__ down,
        const int* __restrict__ nmt, const int* __restrict__ te,
        const int* __restrict__ tr0, const int* __restrict__ trn,
        const int* __restrict__ pair_tok, float* __restrict__ out){
    __shared__ __align__(16) unsigned short As[2][BM*32];
    __shared__ __align__(16) unsigned short Bs[2][BM*40];
    __shared__ int s_tok[BM];

    TILE_DECODE()
    const int n0 = nt*128;

    const int t = threadIdx.x;
    if (t < BM){
        int p = row0 + t; if (p > NPAIRS-1) p = NPAIRS-1;
        s_tok[t] = pair_tok[p];
    }
    __syncthreads();

    const int w = t>>6, lane = t&63;
    const int l15 = lane & 15, kb = lane >> 4;
    const int wr = w & 1, wc = w >> 1;
    const int sA = (l15>>1)&3;

    const int arow = w*16 + (lane>>2);
    const int ck0 = (lane&3) ^ ((lane>>3)&3);
    int ap = row0 + arow; if (ap > NPAIRS-1) ap = NPAIRS-1;
    const unsigned short* asrc = gated + (size_t)ap*INTER + ck0*8;

    const int col4 = (t&31)*4;
    const int bd0  = (t>>5)*2;
    const unsigned wb = (unsigned)(col4*80 + (((bd0>>3) ^ ((col4>>3)&3))<<4) + (bd0&7)*2);
    const float* bsrc = down + (size_t)e*INTER*HIDDEN + (size_t)bd0*HIDDEN + (n0 + col4);

    fx4 acc[4][2];
#pragma unroll
    for (int i=0;i<4;i++){ acc[i][0]=(fx4)0.f; acc[i][1]=(fx4)0.f; }

    float4 rv0, rv1;
#define LOADB2(KS) do{ const float* _bp = bsrc + (size_t)(KS)*BK*HIDDEN;        \
    rv0 = *(const float4*)(_bp); rv1 = *(const float4*)(_bp + HIDDEN); }while(0)
#define WRITEB2(BUF) do{ char* _bb = (char*)Bs[BUF];                            \
    *(unsigned*)(_bb + wb      ) = pack2bf(rv0.x, rv1.x);                       \
    *(unsigned*)(_bb + wb +  80) = pack2bf(rv0.y, rv1.y);                       \
    *(unsigned*)(_bb + wb + 160) = pack2bf(rv0.z, rv1.z);                       \
    *(unsigned*)(_bb + wb + 240) = pack2bf(rv0.w, rv1.w); }while(0)
#define STAGEA2(KS,BUF) gload_lds16(asrc + (KS)*BK, &As[BUF][(w*16)*32])

    STAGEA2(0,0); LOADB2(0);
    __syncthreads();
    WRITEB2(0);
    __syncthreads();

    for (int k=0;k<NK2;k++){
        const int kn = k+1;
        if (kn < NK2){ LOADB2(kn); STAGEA2(kn, kn&1); }
        {
            const unsigned short* _Ak = As[k&1];
            const char* _Bb = (const char*)Bs[k&1];
            bh8 _a0 = *(const bh8*)(_Ak + (wr*64      + l15)*32 + ((kb^sA)<<3));
            bh8 _a1 = *(const bh8*)(_Ak + (wr*64 + 16 + l15)*32 + ((kb^sA)<<3));
            bh8 _a2 = *(const bh8*)(_Ak + (wr*64 + 32 + l15)*32 + ((kb^sA)<<3));
            bh8 _a3 = *(const bh8*)(_Ak + (wr*64 + 48 + l15)*32 + ((kb^sA)<<3));
            const int bc0 = wc*16 + l15, bc1 = 64 + wc*16 + l15;
            bh8 _b0 = *(const bh8*)(_Bb + bc0*80 + ((kb ^ ((bc0>>3)&3))<<4));
            bh8 _b1 = *(const bh8*)(_Bb + bc1*80 + ((kb ^ ((bc1>>3)&3))<<4));
            acc[0][0]=MFMA16(_a0,_b0,acc[0][0]); acc[0][1]=MFMA16(_a0,_b1,acc[0][1]);
            acc[1][0]=MFMA16(_a1,_b0,acc[1][0]); acc[1][1]=MFMA16(_a1,_b1,acc[1][1]);
            acc[2][0]=MFMA16(_a2,_b0,acc[2][0]); acc[2][1]=MFMA16(_a2,_b1,acc[2][1]);
            acc[3][0]=MFMA16(_a3,_b0,acc[3][0]); acc[3][1]=MFMA16(_a3,_b1,acc[3][1]);
        }
        __syncthreads();
        if (kn < NK2) WRITEB2(kn&1);
        __syncthreads();
    }

#pragma unroll
    for (int mr=0;mr<4;mr++){
#pragma unroll
        for (int qq=0;qq<4;qq++){
            int row = wr*64 + mr*16 + kb*4 + qq;
            if (row < rows){
                float* orow = out + (size_t)s_tok[row]*HIDDEN + n0 + wc*16 + l15;
                atomicAdd(orow,      acc[mr][0][qq]);
                atomicAdd(orow + 64, acc[mr][1][qq]);
            }
        }
    }
#undef LOADB2
#undef WRITEB2
#undef STAGEA2
}

/* ---------------- host launch ---------------- */
extern "C" void kernel_launch(void* const* d_in, const int* in_sizes, int n_in,
                              void* d_out, int out_size, void* d_ws, size_t ws_size,
                              hipStream_t stream){
    const float* x    = (const float*)d_in[0];
    const float* gate = (const float*)d_in[1];
    const float* gup  = (const float*)d_in[2];
    const float* down = (const float*)d_in[3];
    float* out = (float*)d_out;
    char*  ws  = (char*)d_ws;

    int*   topk_id  = (int*)  (ws + 0x00000);
    float* topk_w   = (float*)(ws + 0x08000);
    int*   counts   = (int*)  (ws + 0x10000);
    int*   cursors  = (int*)  (ws + 0x10080);
    int*   offs     = (int*)  (ws + 0x10100);
    int*   nmt      = (int*)  (ws + 0x10180);
    int*   te       = (int*)  (ws + 0x10200);
    int*   tr0      = (int*)  (ws + 0x10400);
    int*   trn      = (int*)  (ws + 0x10600);
    int*   pair_tok = (int*)  (ws + 0x10800);
    float* pair_w   = (float*)(ws + 0x18800);
    unsigned short* gated      = (unsigned short*)(ws + 0x21000);   // 12.6MB
    unsigned short* xb         = (unsigned short*)(ws + 0xC60000);  // 8MB
    unsigned short* gated_dead = (unsigned short*)(ws + 0x1460000); // 12.6MB scratch (ablation)

    hipMemsetAsync(d_out, 0, (size_t)out_size*sizeof(float), stream);
    hipMemsetAsync(counts, 0, NEXPERT*sizeof(int), stream);

    cvt_x_k  <<<T_TOKENS*HIDDEN/(256*8), 256, 0, stream>>>(x, xb);
    router_k <<<T_TOKENS, 64, 0, stream>>>(x, gate, topk_id, topk_w, counts);
    sched_k  <<<1, 64, 0, stream>>>(counts, offs, cursors, nmt, te, tr0, trn);
    scatter_k<<<NPAIRS/256, 256, 0, stream>>>(topk_id, topk_w, cursors, pair_tok, pair_w);

    gemm1_t<0><<<MT_MAX*NT1, 512, 0, stream>>>(xb, gup, nmt, te, tr0, trn, pair_tok, pair_w, gated);
    gemm2_k   <<<MT_MAX*NT2, 512, 0, stream>>>(gated, down, nmt, te, tr0, trn, pair_tok, out);

    /* ---- diagnostic ablations (dead output, run after real pipeline) ---- */
    gemm1_t<1><<<MT_MAX*NT1, 512, 0, stream>>>(xb, gup, nmt, te, tr0, trn, pair_tok, pair_w, gated_dead);
    gemm1_t<2><<<MT_MAX*NT1, 512, 0, stream>>>(xb, gup, nmt, te, tr0, trn, pair_tok, pair_w, gated_dead);
    gemm1_t<3><<<MT_MAX*NT1, 512, 0, stream>>>(xb, gup, nmt, te, tr0, trn, pair_tok, pair_w, gated_dead);
}

// Round 9
// 505.750 us; speedup vs baseline: 1.6363x; 1.6363x over previous
//
#include <hip/hip_runtime.h>

#define T_TOKENS 2048
#define HIDDEN   2048
#define NEXPERT  32
#define TOPK     4
#define INTER    768
#define NPAIRS   (T_TOKENS*TOPK)   /* 8192 */
#define BM       128
#define BK       32
#define MT_MAX   95                /* sum ceil(cnt/128) <= 64 + 31 */
#define NT1      12                /* 768/64 feature tiles (64 g + 64 u rows) */
#define NT2      16                /* 2048/128 out col tiles */
#define NK1      (HIDDEN/BK)       /* 64 */
#define NK2      (INTER/BK)        /* 24 */

typedef short  bh8 __attribute__((ext_vector_type(8)));   // 8 bf16
typedef float  fx4 __attribute__((ext_vector_type(4)));

#define AS1 __attribute__((address_space(1)))
#define AS3 __attribute__((address_space(3)))

__device__ __forceinline__ void gload_lds16(const void* g, const void* lds_generic){
    __builtin_amdgcn_global_load_lds(
        (const AS1 void*)(unsigned long long)g,
        (AS3 void*)(unsigned int)(unsigned long long)lds_generic,
        16, 0, 0);
}

__device__ __forceinline__ unsigned int pack2bf(float a, float b){
    unsigned ua = __float_as_uint(a) + 0x8000u;
    unsigned ub = __float_as_uint(b) + 0x8000u;
    return __builtin_amdgcn_perm(ub, ua, 0x07060302u);
}
__device__ __forceinline__ unsigned short f2bfu(float f){
    return (unsigned short)((__float_as_uint(f) + 0x8000u) >> 16);
}

/* ---------------- x -> bf16 ---------------- */
__global__ void cvt_x_k(const float* __restrict__ x, unsigned short* __restrict__ xb){
    int i = (blockIdx.x*256 + threadIdx.x)*8;
    float4 a = *(const float4*)(x+i);
    float4 b = *(const float4*)(x+i+4);
    uint4 o;
    o.x = pack2bf(a.x,a.y); o.y = pack2bf(a.z,a.w);
    o.z = pack2bf(b.x,b.y); o.w = pack2bf(b.z,b.w);
    *(uint4*)(xb+i) = o;
}

/* ---------------- router ---------------- */
__global__ void router_k(const float* __restrict__ x, const float* __restrict__ gate,
                         int* __restrict__ topk_id, float* __restrict__ topk_w,
                         int* __restrict__ counts){
    const int t = blockIdx.x;
    const int l = threadIdx.x;
    const float* xr = x + (size_t)t*HIDDEN;
    float acc[NEXPERT];
#pragma unroll
    for (int e=0;e<NEXPERT;e++) acc[e]=0.f;
    for (int d=l; d<HIDDEN; d+=64){
        float xv = xr[d];
        const float4* g4 = (const float4*)(gate + (size_t)d*NEXPERT);
#pragma unroll
        for (int i=0;i<8;i++){
            float4 g = g4[i];
            acc[i*4+0] += xv*g.x; acc[i*4+1] += xv*g.y;
            acc[i*4+2] += xv*g.z; acc[i*4+3] += xv*g.w;
        }
    }
#pragma unroll
    for (int e=0;e<NEXPERT;e++){
#pragma unroll
        for (int m=1;m<64;m<<=1) acc[e] += __shfl_xor(acc[e], m, 64);
    }
    int ids[TOPK]; float lv[TOPK];
#pragma unroll
    for (int k=0;k<TOPK;k++){
        float m=-1e30f; int mi=0;
#pragma unroll
        for (int e=0;e<NEXPERT;e++){ if (acc[e]>m){ m=acc[e]; mi=e; } }
        ids[k]=mi; lv[k]=m; acc[mi]=-1e30f;
    }
    float ex[TOPK]; float s=0.f;
#pragma unroll
    for (int k=0;k<TOPK;k++){ ex[k]=__expf(lv[k]-lv[0]); s+=ex[k]; }
    if (l==0){
        float inv = 1.f/s;
#pragma unroll
        for (int k=0;k<TOPK;k++){
            topk_id[t*TOPK+k]=ids[k];
            topk_w[t*TOPK+k]=ex[k]*inv;
            atomicAdd(&counts[ids[k]],1);
        }
    }
}

/* ---------------- schedule ---------------- */
__global__ void sched_k(const int* __restrict__ counts, int* __restrict__ offs,
                        int* __restrict__ cursors, int* __restrict__ nmt,
                        int* __restrict__ te, int* __restrict__ tr0, int* __restrict__ trn){
    if (threadIdx.x==0 && blockIdx.x==0){
        int tot=0, nm=0;
        for (int e=0;e<NEXPERT;e++){
            int c = counts[e];
            offs[e]=tot; cursors[e]=tot;
            for (int s=0;s<c;s+=BM){
                te[nm]=e; tr0[nm]=tot+s; trn[nm]=(c-s)<BM?(c-s):BM; nm++;
            }
            tot+=c;
        }
        *nmt = nm;
    }
}

/* ---------------- scatter ---------------- */
__global__ void scatter_k(const int* __restrict__ topk_id, const float* __restrict__ topk_w,
                          int* __restrict__ cursors, int* __restrict__ pair_tok,
                          float* __restrict__ pair_w){
    int g = blockIdx.x*256 + threadIdx.x;
    int e = topk_id[g];
    float w = topk_w[g];
    int pos = atomicAdd(&cursors[e],1);
    pair_tok[pos] = g>>2;
    pair_w[pos]  = w;
}

/* ======== pre-pass 1: gup [e][2048][1536] f32 -> wT1 tiled bf16 ========
   block b = (e*12+nt)*64+ks : 8KB tile, rows 0..63 = g(n0..n0+63), 64..127 = u. */
__global__ __launch_bounds__(256) void wt1_k(const float* __restrict__ gup,
                                             unsigned short* __restrict__ wT1){
    __shared__ unsigned short L[128*40];
    const int b = blockIdx.x;
    const int ks = b & 63, nt = (b>>6) % NT1, e = b / (64*NT1);
    const int t = threadIdx.x;
    const int s = t>>7, t7 = t&127;
    const int kk = t7>>2, fq = (t7&3)*16;
    const float* src = gup + ((size_t)e*HIDDEN + (size_t)ks*BK + kk)*(2*INTER)
                           + (s ? 768 + nt*64 : nt*64) + fq;
    float4 v0 = ((const float4*)src)[0];
    float4 v1 = ((const float4*)src)[1];
    float4 v2 = ((const float4*)src)[2];
    float4 v3 = ((const float4*)src)[3];
    const int fb = s*64 + fq;
    L[(fb+ 0)*40+kk]=f2bfu(v0.x); L[(fb+ 1)*40+kk]=f2bfu(v0.y);
    L[(fb+ 2)*40+kk]=f2bfu(v0.z); L[(fb+ 3)*40+kk]=f2bfu(v0.w);
    L[(fb+ 4)*40+kk]=f2bfu(v1.x); L[(fb+ 5)*40+kk]=f2bfu(v1.y);
    L[(fb+ 6)*40+kk]=f2bfu(v1.z); L[(fb+ 7)*40+kk]=f2bfu(v1.w);
    L[(fb+ 8)*40+kk]=f2bfu(v2.x); L[(fb+ 9)*40+kk]=f2bfu(v2.y);
    L[(fb+10)*40+kk]=f2bfu(v2.z); L[(fb+11)*40+kk]=f2bfu(v2.w);
    L[(fb+12)*40+kk]=f2bfu(v3.x); L[(fb+13)*40+kk]=f2bfu(v3.y);
    L[(fb+14)*40+kk]=f2bfu(v3.z); L[(fb+15)*40+kk]=f2bfu(v3.w);
    __syncthreads();
    const int f2 = t>>1, kc = t&1;
    uint4 o0 = *(const uint4*)&L[f2*40 + kc*16];
    uint4 o1 = *(const uint4*)&L[f2*40 + kc*16 + 8];
    unsigned short* dst = wT1 + (size_t)b*4096 + t*16;
    ((uint4*)dst)[0] = o0;
    ((uint4*)dst)[1] = o1;
}

/* ======== pre-pass 2: down [e][768][2048] f32 -> wT2 tiled bf16 ========
   block b = (e*16+nt)*24+ks : 8KB tile, rows = out-cols n0..n0+127. */
__global__ __launch_bounds__(256) void wt2_k(const float* __restrict__ down,
                                             unsigned short* __restrict__ wT2){
    __shared__ unsigned short L[128*40];
    const int b = blockIdx.x;
    const int ks = b % NK2, nt = (b/NK2) % NT2, e = b / (NK2*NT2);
    const int t = threadIdx.x;
    const int kk = t>>3, nq = (t&7)*16;
    const float* src = down + ((size_t)e*INTER + (size_t)ks*BK + kk)*HIDDEN
                            + nt*128 + nq;
    float4 v0 = ((const float4*)src)[0];
    float4 v1 = ((const float4*)src)[1];
    float4 v2 = ((const float4*)src)[2];
    float4 v3 = ((const float4*)src)[3];
    L[(nq+ 0)*40+kk]=f2bfu(v0.x); L[(nq+ 1)*40+kk]=f2bfu(v0.y);
    L[(nq+ 2)*40+kk]=f2bfu(v0.z); L[(nq+ 3)*40+kk]=f2bfu(v0.w);
    L[(nq+ 4)*40+kk]=f2bfu(v1.x); L[(nq+ 5)*40+kk]=f2bfu(v1.y);
    L[(nq+ 6)*40+kk]=f2bfu(v1.z); L[(nq+ 7)*40+kk]=f2bfu(v1.w);
    L[(nq+ 8)*40+kk]=f2bfu(v2.x); L[(nq+ 9)*40+kk]=f2bfu(v2.y);
    L[(nq+10)*40+kk]=f2bfu(v2.z); L[(nq+11)*40+kk]=f2bfu(v2.w);
    L[(nq+12)*40+kk]=f2bfu(v3.x); L[(nq+13)*40+kk]=f2bfu(v3.y);
    L[(nq+14)*40+kk]=f2bfu(v3.z); L[(nq+15)*40+kk]=f2bfu(v3.w);
    __syncthreads();
    const int f2 = t>>1, kc = t&1;
    uint4 o0 = *(const uint4*)&L[f2*40 + kc*16];
    uint4 o1 = *(const uint4*)&L[f2*40 + kc*16 + 8];
    unsigned short* dst = wT2 + (size_t)b*4096 + t*16;
    ((uint4*)dst)[0] = o0;
    ((uint4*)dst)[1] = o1;
}

/* tile-id decode: bijective XCD-chunked swizzle, mt innermost (B-tile L2 reuse) */
#define TILE_DECODE()                                              \
    const int nwg = gridDim.x;                                     \
    const int q = nwg>>3, r = nwg&7;                               \
    const int xcd = blockIdx.x & 7, bidx = blockIdx.x >> 3;        \
    const int L = (xcd<r ? xcd*(q+1) : r*(q+1)+(xcd-r)*q) + bidx;  \
    const int mt = L % MT_MAX, nt = L / MT_MAX;                    \
    if (mt >= *nmt) return;                                        \
    const int e = te[mt], row0 = tr0[mt], rows = trn[mt];

#define MFMA16(A,B,C) __builtin_amdgcn_mfma_f32_16x16x32_bf16(A,B,C,0,0,0)

/* ============== GEMM1 (m97-form): xb x wT1 -> gated(bf16, silu fused) ============== */
__global__ __launch_bounds__(256,3) void gemm1_k(
        const unsigned short* __restrict__ xb, const unsigned short* __restrict__ wT1,
        const int* __restrict__ nmt, const int* __restrict__ te,
        const int* __restrict__ tr0, const int* __restrict__ trn,
        const int* __restrict__ pair_tok, const float* __restrict__ pair_w,
        unsigned short* __restrict__ gated){
    __shared__ __align__(16) unsigned short As[2][BM*32];   // [row][32k] 64B rows
    __shared__ __align__(16) unsigned short Bs[2][BM*32];
    __shared__ int   s_tok[BM];
    __shared__ float s_w[BM];

    TILE_DECODE()
    const int n0 = nt*64;

    const int t = threadIdx.x;
    if (t < BM){
        int p = row0 + t; if (p > NPAIRS-1) p = NPAIRS-1;
        s_tok[t] = pair_tok[p];
        s_w[t]   = pair_w[p];
    }
    __syncthreads();

    const int w = t>>6, lane = t&63;
    const int l15 = lane & 15, kb = lane >> 4;
    const int wr = w & 1, wc = w >> 1;

    // A DMA: call-site c covers rows c*64 + w*16 + lane/4, chunk lane%4
    const int ar0 = w*16 + (lane>>2), ar1 = 64 + ar0;
    const unsigned short* asrc0 = xb + (size_t)s_tok[ar0]*HIDDEN + (lane&3)*8;
    const unsigned short* asrc1 = xb + (size_t)s_tok[ar1]*HIDDEN + (lane&3)*8;
    // B DMA: pre-tiled linear stream
    const unsigned short* bsrc = wT1 + ((size_t)(e*NT1 + nt)*NK1)*4096 + w*512 + lane*8;

    fx4 acc[4][4];
#pragma unroll
    for (int i=0;i<4;i++)
#pragma unroll
        for (int j=0;j<4;j++) acc[i][j] = (fx4)0.f;

#define DMA1(BUF,KS) do{                                                        \
    gload_lds16(asrc0 + (KS)*BK,            &As[BUF][ w*512      ]);            \
    gload_lds16(asrc1 + (KS)*BK,            &As[BUF][2048 + w*512]);            \
    gload_lds16(bsrc + (size_t)(KS)*4096,   &Bs[BUF][ w*512      ]);            \
    gload_lds16(bsrc + (size_t)(KS)*4096+2048, &Bs[BUF][2048 + w*512]);         \
}while(0)

    DMA1(0,0);
    for (int k=0;k<NK1;k++){
        __syncthreads();
        if (k+1 < NK1) DMA1((k+1)&1, k+1);
        const unsigned short* Ak = As[k&1];
        const unsigned short* Bk = Bs[k&1];
        bh8 a0 = *(const bh8*)(Ak + (wr*64      + l15)*32 + kb*8);
        bh8 a1 = *(const bh8*)(Ak + (wr*64 + 16 + l15)*32 + kb*8);
        bh8 a2 = *(const bh8*)(Ak + (wr*64 + 32 + l15)*32 + kb*8);
        bh8 a3 = *(const bh8*)(Ak + (wr*64 + 48 + l15)*32 + kb*8);
#pragma unroll
        for (int ni=0;ni<4;ni++){
            const int br = (ni<2) ? (wc*32 + ni*16 + l15)
                                  : (64 + wc*32 + (ni-2)*16 + l15);
            bh8 b = *(const bh8*)(Bk + br*32 + kb*8);
            acc[0][ni]=MFMA16(a0,b,acc[0][ni]);
            acc[1][ni]=MFMA16(a1,b,acc[1][ni]);
            acc[2][ni]=MFMA16(a2,b,acc[2][ni]);
            acc[3][ni]=MFMA16(a3,b,acc[3][ni]);
        }
    }

    // epilogue: silu(g)*u*w  (g=acc[mi][ni2], u=acc[mi][ni2+2], same feature)
#pragma unroll
    for (int mi=0;mi<4;mi++){
#pragma unroll
        for (int qq=0;qq<4;qq++){
            int row = wr*64 + mi*16 + kb*4 + qq;
            if (row < rows){
                float wgt = s_w[row];
                size_t prow = (size_t)(row0 + row)*INTER + n0 + wc*32 + l15;
#pragma unroll
                for (int ni2=0;ni2<2;ni2++){
                    float g = acc[mi][ni2][qq], u = acc[mi][ni2+2][qq];
                    float sil = g / (1.f + __expf(-g));
                    gated[prow + ni2*16] = f2bfu(sil*u*wgt);
                }
            }
        }
    }
#undef DMA1
}

/* ============== GEMM2 (m97-form): gated x wT2 -> out (atomic f32) ============== */
__global__ __launch_bounds__(256,3) void gemm2_k(
        const unsigned short* __restrict__ gated, const unsigned short* __restrict__ wT2,
        const int* __restrict__ nmt, const int* __restrict__ te,
        const int* __restrict__ tr0, const int* __restrict__ trn,
        const int* __restrict__ pair_tok, float* __restrict__ out){
    __shared__ __align__(16) unsigned short As[2][BM*32];
    __shared__ __align__(16) unsigned short Bs[2][BM*32];
    __shared__ int s_tok[BM];

    TILE_DECODE()
    const int n0 = nt*128;

    const int t = threadIdx.x;
    if (t < BM){
        int p = row0 + t; if (p > NPAIRS-1) p = NPAIRS-1;
        s_tok[t] = pair_tok[p];
    }
    __syncthreads();

    const int w = t>>6, lane = t&63;
    const int l15 = lane & 15, kb = lane >> 4;
    const int wr = w & 1, wc = w >> 1;

    const int ar0 = w*16 + (lane>>2), ar1 = 64 + ar0;
    int ap0 = row0 + ar0; if (ap0 > NPAIRS-1) ap0 = NPAIRS-1;
    int ap1 = row0 + ar1; if (ap1 > NPAIRS-1) ap1 = NPAIRS-1;
    const unsigned short* asrc0 = gated + (size_t)ap0*INTER + (lane&3)*8;
    const unsigned short* asrc1 = gated + (size_t)ap1*INTER + (lane&3)*8;
    const unsigned short* bsrc = wT2 + ((size_t)(e*NT2 + nt)*NK2)*4096 + w*512 + lane*8;

    fx4 acc[4][4];
#pragma unroll
    for (int i=0;i<4;i++)
#pragma unroll
        for (int j=0;j<4;j++) acc[i][j] = (fx4)0.f;

#define DMA2(BUF,KS) do{                                                        \
    gload_lds16(asrc0 + (KS)*BK,            &As[BUF][ w*512      ]);            \
    gload_lds16(asrc1 + (KS)*BK,            &As[BUF][2048 + w*512]);            \
    gload_lds16(bsrc + (size_t)(KS)*4096,   &Bs[BUF][ w*512      ]);            \
    gload_lds16(bsrc + (size_t)(KS)*4096+2048, &Bs[BUF][2048 + w*512]);         \
}while(0)

    DMA2(0,0);
    for (int k=0;k<NK2;k++){
        __syncthreads();
        if (k+1 < NK2) DMA2((k+1)&1, k+1);
        const unsigned short* Ak = As[k&1];
        const unsigned short* Bk = Bs[k&1];
        bh8 a0 = *(const bh8*)(Ak + (wr*64      + l15)*32 + kb*8);
        bh8 a1 = *(const bh8*)(Ak + (wr*64 + 16 + l15)*32 + kb*8);
        bh8 a2 = *(const bh8*)(Ak + (wr*64 + 32 + l15)*32 + kb*8);
        bh8 a3 = *(const bh8*)(Ak + (wr*64 + 48 + l15)*32 + kb*8);
#pragma unroll
        for (int ni=0;ni<4;ni++){
            const int br = wc*64 + ni*16 + l15;
            bh8 b = *(const bh8*)(Bk + br*32 + kb*8);
            acc[0][ni]=MFMA16(a0,b,acc[0][ni]);
            acc[1][ni]=MFMA16(a1,b,acc[1][ni]);
            acc[2][ni]=MFMA16(a2,b,acc[2][ni]);
            acc[3][ni]=MFMA16(a3,b,acc[3][ni]);
        }
    }

#pragma unroll
    for (int mi=0;mi<4;mi++){
#pragma unroll
        for (int qq=0;qq<4;qq++){
            int row = wr*64 + mi*16 + kb*4 + qq;
            if (row < rows){
                float* orow = out + (size_t)s_tok[row]*HIDDEN + n0 + wc*64 + l15;
#pragma unroll
                for (int ni=0;ni<4;ni++)
                    atomicAdd(orow + ni*16, acc[mi][ni][qq]);
            }
        }
    }
#undef DMA2
}

/* ---------------- host launch ---------------- */
extern "C" void kernel_launch(void* const* d_in, const int* in_sizes, int n_in,
                              void* d_out, int out_size, void* d_ws, size_t ws_size,
                              hipStream_t stream){
    const float* x    = (const float*)d_in[0];
    const float* gate = (const float*)d_in[1];
    const float* gup  = (const float*)d_in[2];
    const float* down = (const float*)d_in[3];
    float* out = (float*)d_out;
    char*  ws  = (char*)d_ws;

    int*   topk_id  = (int*)  (ws + 0x00000);
    float* topk_w   = (float*)(ws + 0x08000);
    int*   counts   = (int*)  (ws + 0x10000);
    int*   cursors  = (int*)  (ws + 0x10080);
    int*   offs     = (int*)  (ws + 0x10100);
    int*   nmt      = (int*)  (ws + 0x10180);
    int*   te       = (int*)  (ws + 0x10200);
    int*   tr0      = (int*)  (ws + 0x10400);
    int*   trn      = (int*)  (ws + 0x10600);
    int*   pair_tok = (int*)  (ws + 0x10800);
    float* pair_w   = (float*)(ws + 0x18800);
    unsigned short* gated = (unsigned short*)(ws + 0x21000);     // 8320*768*2 = 12.8MB
    unsigned short* xb    = (unsigned short*)(ws + 0xC60000);    // 8MB
    unsigned short* wT1   = (unsigned short*)(ws + 0x1460000);   // 32*12*64*8KB = 201.3MB
    unsigned short* wT2   = (unsigned short*)(ws + 0xD460000);   // 32*16*24*8KB = 100.7MB

    hipMemsetAsync(d_out, 0, (size_t)out_size*sizeof(float), stream);
    hipMemsetAsync(counts, 0, NEXPERT*sizeof(int), stream);

    cvt_x_k  <<<T_TOKENS*HIDDEN/(256*8), 256, 0, stream>>>(x, xb);
    router_k <<<T_TOKENS, 64, 0, stream>>>(x, gate, topk_id, topk_w, counts);
    sched_k  <<<1, 64, 0, stream>>>(counts, offs, cursors, nmt, te, tr0, trn);
    scatter_k<<<NPAIRS/256, 256, 0, stream>>>(topk_id, topk_w, cursors, pair_tok, pair_w);

    wt1_k    <<<NEXPERT*NT1*NK1, 256, 0, stream>>>(gup,  wT1);   // 24576 blocks
    wt2_k    <<<NEXPERT*NT2*NK2, 256, 0, stream>>>(down, wT2);   // 12288 blocks

    gemm1_k  <<<MT_MAX*NT1, 256, 0, stream>>>(xb, wT1, nmt, te, tr0, trn, pair_tok, pair_w, gated);
    gemm2_k  <<<MT_MAX*NT2, 256, 0, stream>>>(gated, wT2, nmt, te, tr0, trn, pair_tok, out);
}

// Round 10
// 496.157 us; speedup vs baseline: 1.6680x; 1.0193x over previous
//
#include <hip/hip_runtime.h>

#define T_TOKENS 2048
#define HIDDEN   2048
#define NEXPERT  32
#define TOPK     4
#define INTER    768
#define NPAIRS   (T_TOKENS*TOPK)   /* 8192 */
#define BM       128
#define BK       32
#define MT_MAX   95                /* sum ceil(cnt/128) <= 64 + 31 */
#define NT1      12                /* 768/64 feature tiles (64 g + 64 u rows) */
#define NT2      16                /* 2048/128 out col tiles */
#define NK1      (HIDDEN/BK)       /* 64 */
#define NK2      (INTER/BK)        /* 24 */

typedef short  bh8 __attribute__((ext_vector_type(8)));   // 8 bf16
typedef float  fx4 __attribute__((ext_vector_type(4)));

#define AS1 __attribute__((address_space(1)))
#define AS3 __attribute__((address_space(3)))

__device__ __forceinline__ void gload_lds16(const void* g, const void* lds_generic){
    __builtin_amdgcn_global_load_lds(
        (const AS1 void*)(unsigned long long)g,
        (AS3 void*)(unsigned int)(unsigned long long)lds_generic,
        16, 0, 0);
}

__device__ __forceinline__ unsigned int pack2bf(float a, float b){
    unsigned ua = __float_as_uint(a) + 0x8000u;
    unsigned ub = __float_as_uint(b) + 0x8000u;
    return __builtin_amdgcn_perm(ub, ua, 0x07060302u);
}
__device__ __forceinline__ unsigned short f2bfu(float f){
    return (unsigned short)((__float_as_uint(f) + 0x8000u) >> 16);
}

/* ---------------- x -> bf16 ---------------- */
__global__ void cvt_x_k(const float* __restrict__ x, unsigned short* __restrict__ xb){
    int i = (blockIdx.x*256 + threadIdx.x)*8;
    float4 a = *(const float4*)(x+i);
    float4 b = *(const float4*)(x+i+4);
    uint4 o;
    o.x = pack2bf(a.x,a.y); o.y = pack2bf(a.z,a.w);
    o.z = pack2bf(b.x,b.y); o.w = pack2bf(b.z,b.w);
    *(uint4*)(xb+i) = o;
}

/* ---------------- router ---------------- */
__global__ void router_k(const float* __restrict__ x, const float* __restrict__ gate,
                         int* __restrict__ topk_id, float* __restrict__ topk_w,
                         int* __restrict__ counts){
    const int t = blockIdx.x;
    const int l = threadIdx.x;
    const float* xr = x + (size_t)t*HIDDEN;
    float acc[NEXPERT];
#pragma unroll
    for (int e=0;e<NEXPERT;e++) acc[e]=0.f;
    for (int d=l; d<HIDDEN; d+=64){
        float xv = xr[d];
        const float4* g4 = (const float4*)(gate + (size_t)d*NEXPERT);
#pragma unroll
        for (int i=0;i<8;i++){
            float4 g = g4[i];
            acc[i*4+0] += xv*g.x; acc[i*4+1] += xv*g.y;
            acc[i*4+2] += xv*g.z; acc[i*4+3] += xv*g.w;
        }
    }
#pragma unroll
    for (int e=0;e<NEXPERT;e++){
#pragma unroll
        for (int m=1;m<64;m<<=1) acc[e] += __shfl_xor(acc[e], m, 64);
    }
    int ids[TOPK]; float lv[TOPK];
#pragma unroll
    for (int k=0;k<TOPK;k++){
        float m=-1e30f; int mi=0;
#pragma unroll
        for (int e=0;e<NEXPERT;e++){ if (acc[e]>m){ m=acc[e]; mi=e; } }
        ids[k]=mi; lv[k]=m; acc[mi]=-1e30f;
    }
    float ex[TOPK]; float s=0.f;
#pragma unroll
    for (int k=0;k<TOPK;k++){ ex[k]=__expf(lv[k]-lv[0]); s+=ex[k]; }
    if (l==0){
        float inv = 1.f/s;
#pragma unroll
        for (int k=0;k<TOPK;k++){
            topk_id[t*TOPK+k]=ids[k];
            topk_w[t*TOPK+k]=ex[k]*inv;
            atomicAdd(&counts[ids[k]],1);
        }
    }
}

/* ---------------- schedule ---------------- */
__global__ void sched_k(const int* __restrict__ counts, int* __restrict__ offs,
                        int* __restrict__ cursors, int* __restrict__ nmt,
                        int* __restrict__ te, int* __restrict__ tr0, int* __restrict__ trn){
    if (threadIdx.x==0 && blockIdx.x==0){
        int tot=0, nm=0;
        for (int e=0;e<NEXPERT;e++){
            int c = counts[e];
            offs[e]=tot; cursors[e]=tot;
            for (int s=0;s<c;s+=BM){
                te[nm]=e; tr0[nm]=tot+s; trn[nm]=(c-s)<BM?(c-s):BM; nm++;
            }
            tot+=c;
        }
        *nmt = nm;
    }
}

/* ---------------- scatter ---------------- */
__global__ void scatter_k(const int* __restrict__ topk_id, const float* __restrict__ topk_w,
                          int* __restrict__ cursors, int* __restrict__ pair_tok,
                          float* __restrict__ pair_w){
    int g = blockIdx.x*256 + threadIdx.x;
    int e = topk_id[g];
    float w = topk_w[g];
    int pos = atomicAdd(&cursors[e],1);
    pair_tok[pos] = g>>2;
    pair_w[pos]  = w;
}

/* ======== pre-pass 1: gup [e][2048][1536] f32 -> wT1 tiled bf16 ========
   block b = (e*12+nt)*64+ks : 8KB tile, rows 0..63 = g(n0..n0+63), 64..127 = u. */
__global__ __launch_bounds__(256) void wt1_k(const float* __restrict__ gup,
                                             unsigned short* __restrict__ wT1){
    __shared__ unsigned short L[128*40];
    const int b = blockIdx.x;
    const int ks = b & 63, nt = (b>>6) % NT1, e = b / (64*NT1);
    const int t = threadIdx.x;
    const int s = t>>7, t7 = t&127;
    const int kk = t7>>2, fq = (t7&3)*16;
    const float* src = gup + ((size_t)e*HIDDEN + (size_t)ks*BK + kk)*(2*INTER)
                           + (s ? 768 + nt*64 : nt*64) + fq;
    float4 v0 = ((const float4*)src)[0];
    float4 v1 = ((const float4*)src)[1];
    float4 v2 = ((const float4*)src)[2];
    float4 v3 = ((const float4*)src)[3];
    const int fb = s*64 + fq;
    L[(fb+ 0)*40+kk]=f2bfu(v0.x); L[(fb+ 1)*40+kk]=f2bfu(v0.y);
    L[(fb+ 2)*40+kk]=f2bfu(v0.z); L[(fb+ 3)*40+kk]=f2bfu(v0.w);
    L[(fb+ 4)*40+kk]=f2bfu(v1.x); L[(fb+ 5)*40+kk]=f2bfu(v1.y);
    L[(fb+ 6)*40+kk]=f2bfu(v1.z); L[(fb+ 7)*40+kk]=f2bfu(v1.w);
    L[(fb+ 8)*40+kk]=f2bfu(v2.x); L[(fb+ 9)*40+kk]=f2bfu(v2.y);
    L[(fb+10)*40+kk]=f2bfu(v2.z); L[(fb+11)*40+kk]=f2bfu(v2.w);
    L[(fb+12)*40+kk]=f2bfu(v3.x); L[(fb+13)*40+kk]=f2bfu(v3.y);
    L[(fb+14)*40+kk]=f2bfu(v3.z); L[(fb+15)*40+kk]=f2bfu(v3.w);
    __syncthreads();
    const int f2 = t>>1, kc = t&1;
    uint4 o0 = *(const uint4*)&L[f2*40 + kc*16];
    uint4 o1 = *(const uint4*)&L[f2*40 + kc*16 + 8];
    unsigned short* dst = wT1 + (size_t)b*4096 + t*16;
    ((uint4*)dst)[0] = o0;
    ((uint4*)dst)[1] = o1;
}

/* ======== pre-pass 2: down [e][768][2048] f32 -> wT2 tiled bf16 ========
   block b = (e*16+nt)*24+ks : 8KB tile, rows = out-cols n0..n0+127. */
__global__ __launch_bounds__(256) void wt2_k(const float* __restrict__ down,
                                             unsigned short* __restrict__ wT2){
    __shared__ unsigned short L[128*40];
    const int b = blockIdx.x;
    const int ks = b % NK2, nt = (b/NK2) % NT2, e = b / (NK2*NT2);
    const int t = threadIdx.x;
    const int kk = t>>3, nq = (t&7)*16;
    const float* src = down + ((size_t)e*INTER + (size_t)ks*BK + kk)*HIDDEN
                            + nt*128 + nq;
    float4 v0 = ((const float4*)src)[0];
    float4 v1 = ((const float4*)src)[1];
    float4 v2 = ((const float4*)src)[2];
    float4 v3 = ((const float4*)src)[3];
    L[(nq+ 0)*40+kk]=f2bfu(v0.x); L[(nq+ 1)*40+kk]=f2bfu(v0.y);
    L[(nq+ 2)*40+kk]=f2bfu(v0.z); L[(nq+ 3)*40+kk]=f2bfu(v0.w);
    L[(nq+ 4)*40+kk]=f2bfu(v1.x); L[(nq+ 5)*40+kk]=f2bfu(v1.y);
    L[(nq+ 6)*40+kk]=f2bfu(v1.z); L[(nq+ 7)*40+kk]=f2bfu(v1.w);
    L[(nq+ 8)*40+kk]=f2bfu(v2.x); L[(nq+ 9)*40+kk]=f2bfu(v2.y);
    L[(nq+10)*40+kk]=f2bfu(v2.z); L[(nq+11)*40+kk]=f2bfu(v2.w);
    L[(nq+12)*40+kk]=f2bfu(v3.x); L[(nq+13)*40+kk]=f2bfu(v3.y);
    L[(nq+14)*40+kk]=f2bfu(v3.z); L[(nq+15)*40+kk]=f2bfu(v3.w);
    __syncthreads();
    const int f2 = t>>1, kc = t&1;
    uint4 o0 = *(const uint4*)&L[f2*40 + kc*16];
    uint4 o1 = *(const uint4*)&L[f2*40 + kc*16 + 8];
    unsigned short* dst = wT2 + (size_t)b*4096 + t*16;
    ((uint4*)dst)[0] = o0;
    ((uint4*)dst)[1] = o1;
}

/* tile-id decode: bijective XCD-chunked swizzle, mt innermost (B-tile L2 reuse) */
#define TILE_DECODE()                                              \
    const int nwg = gridDim.x;                                     \
    const int q = nwg>>3, r = nwg&7;                               \
    const int xcd = blockIdx.x & 7, bidx = blockIdx.x >> 3;        \
    const int L = (xcd<r ? xcd*(q+1) : r*(q+1)+(xcd-r)*q) + bidx;  \
    const int mt = L % MT_MAX, nt = L / MT_MAX;                    \
    if (mt >= *nmt) return;                                        \
    const int e = te[mt], row0 = tr0[mt], rows = trn[mt];

#define MFMA16(A,B,C) __builtin_amdgcn_mfma_f32_16x16x32_bf16(A,B,C,0,0,0)

/* ============== GEMM1 (m97-form + counted-vmcnt 3-buf pipeline) ==============
   xb x wT1 -> gated(bf16, silu fused) */
__global__ __launch_bounds__(256,3) void gemm1_k(
        const unsigned short* __restrict__ xb, const unsigned short* __restrict__ wT1,
        const int* __restrict__ nmt, const int* __restrict__ te,
        const int* __restrict__ tr0, const int* __restrict__ trn,
        const int* __restrict__ pair_tok, const float* __restrict__ pair_w,
        unsigned short* __restrict__ gated){
    __shared__ __align__(16) unsigned short As[3][BM*32];   // 3 x 8KB, [row][32k] 64B rows
    __shared__ __align__(16) unsigned short Bs[3][BM*32];
    __shared__ int   s_tok[BM];
    __shared__ float s_w[BM];

    TILE_DECODE()
    const int n0 = nt*64;

    const int t = threadIdx.x;
    if (t < BM){
        int p = row0 + t; if (p > NPAIRS-1) p = NPAIRS-1;
        s_tok[t] = pair_tok[p];
        s_w[t]   = pair_w[p];
    }
    __syncthreads();

    const int w = t>>6, lane = t&63;
    const int l15 = lane & 15, kb = lane >> 4;
    const int wr = w & 1, wc = w >> 1;

    // A DMA: gathered bf16 x rows (4-lane groups of 64B per row)
    const int ar0 = w*16 + (lane>>2), ar1 = 64 + ar0;
    const unsigned short* asrc0 = xb + (size_t)s_tok[ar0]*HIDDEN + (lane&3)*8;
    const unsigned short* asrc1 = xb + (size_t)s_tok[ar1]*HIDDEN + (lane&3)*8;
    // B DMA: pre-tiled linear stream
    const unsigned short* bsrc = wT1 + ((size_t)(e*NT1 + nt)*NK1)*4096 + w*512 + lane*8;

    fx4 acc[4][4];
#pragma unroll
    for (int i=0;i<4;i++)
#pragma unroll
        for (int j=0;j<4;j++) acc[i][j] = (fx4)0.f;

#define DMA1(BUF,KS) do{                                                        \
    gload_lds16(asrc0 + (KS)*BK,               &As[BUF][ w*512      ]);         \
    gload_lds16(asrc1 + (KS)*BK,               &As[BUF][2048 + w*512]);         \
    gload_lds16(bsrc + (size_t)(KS)*4096,      &Bs[BUF][ w*512      ]);         \
    gload_lds16(bsrc + (size_t)(KS)*4096+2048, &Bs[BUF][2048 + w*512]);         \
}while(0)

    // prologue: 2 K-tiles in flight
    DMA1(0,0);
    DMA1(1,1);

    int c0 = 0, c1 = 1, c2 = 2;
    for (int k=0;k<NK1;k++){
        asm volatile("s_waitcnt vmcnt(4)" ::: "memory");   // DMA(k) landed; DMA(k+1) in flight
        __builtin_amdgcn_s_barrier();
        int ks = k+2; if (ks > NK1-1) ks = NK1-1;
        DMA1(c2, ks);                                      // overwrites buf read by MFMA(k-1), done pre-barrier
        const unsigned short* Ak = As[c0];
        const unsigned short* Bk = Bs[c0];
        bh8 a0 = *(const bh8*)(Ak + (wr*64      + l15)*32 + kb*8);
        bh8 a1 = *(const bh8*)(Ak + (wr*64 + 16 + l15)*32 + kb*8);
        bh8 a2 = *(const bh8*)(Ak + (wr*64 + 32 + l15)*32 + kb*8);
        bh8 a3 = *(const bh8*)(Ak + (wr*64 + 48 + l15)*32 + kb*8);
#pragma unroll
        for (int ni=0;ni<4;ni++){
            const int br = (ni<2) ? (wc*32 + ni*16 + l15)
                                  : (64 + wc*32 + (ni-2)*16 + l15);
            bh8 b = *(const bh8*)(Bk + br*32 + kb*8);
            acc[0][ni]=MFMA16(a0,b,acc[0][ni]);
            acc[1][ni]=MFMA16(a1,b,acc[1][ni]);
            acc[2][ni]=MFMA16(a2,b,acc[2][ni]);
            acc[3][ni]=MFMA16(a3,b,acc[3][ni]);
        }
        int tmp = c0; c0 = c1; c1 = c2; c2 = tmp;
    }
    asm volatile("s_waitcnt vmcnt(0)" ::: "memory");

    // epilogue: silu(g)*u*w  (g=acc[mi][ni2], u=acc[mi][ni2+2], same feature)
#pragma unroll
    for (int mi=0;mi<4;mi++){
#pragma unroll
        for (int qq=0;qq<4;qq++){
            int row = wr*64 + mi*16 + kb*4 + qq;
            if (row < rows){
                float wgt = s_w[row];
                size_t prow = (size_t)(row0 + row)*INTER + n0 + wc*32 + l15;
#pragma unroll
                for (int ni2=0;ni2<2;ni2++){
                    float g = acc[mi][ni2][qq], u = acc[mi][ni2+2][qq];
                    float sil = g / (1.f + __expf(-g));
                    gated[prow + ni2*16] = f2bfu(sil*u*wgt);
                }
            }
        }
    }
#undef DMA1
}

/* ============== GEMM2 (m97-form + counted-vmcnt 3-buf pipeline) ==============
   gated x wT2 -> out (atomic f32) */
__global__ __launch_bounds__(256,3) void gemm2_k(
        const unsigned short* __restrict__ gated, const unsigned short* __restrict__ wT2,
        const int* __restrict__ nmt, const int* __restrict__ te,
        const int* __restrict__ tr0, const int* __restrict__ trn,
        const int* __restrict__ pair_tok, float* __restrict__ out){
    __shared__ __align__(16) unsigned short As[3][BM*32];
    __shared__ __align__(16) unsigned short Bs[3][BM*32];
    __shared__ int s_tok[BM];

    TILE_DECODE()
    const int n0 = nt*128;

    const int t = threadIdx.x;
    if (t < BM){
        int p = row0 + t; if (p > NPAIRS-1) p = NPAIRS-1;
        s_tok[t] = pair_tok[p];
    }
    __syncthreads();

    const int w = t>>6, lane = t&63;
    const int l15 = lane & 15, kb = lane >> 4;
    const int wr = w & 1, wc = w >> 1;

    const int ar0 = w*16 + (lane>>2), ar1 = 64 + ar0;
    int ap0 = row0 + ar0; if (ap0 > NPAIRS-1) ap0 = NPAIRS-1;
    int ap1 = row0 + ar1; if (ap1 > NPAIRS-1) ap1 = NPAIRS-1;
    const unsigned short* asrc0 = gated + (size_t)ap0*INTER + (lane&3)*8;
    const unsigned short* asrc1 = gated + (size_t)ap1*INTER + (lane&3)*8;
    const unsigned short* bsrc = wT2 + ((size_t)(e*NT2 + nt)*NK2)*4096 + w*512 + lane*8;

    fx4 acc[4][4];
#pragma unroll
    for (int i=0;i<4;i++)
#pragma unroll
        for (int j=0;j<4;j++) acc[i][j] = (fx4)0.f;

#define DMA2(BUF,KS) do{                                                        \
    gload_lds16(asrc0 + (KS)*BK,               &As[BUF][ w*512      ]);         \
    gload_lds16(asrc1 + (KS)*BK,               &As[BUF][2048 + w*512]);         \
    gload_lds16(bsrc + (size_t)(KS)*4096,      &Bs[BUF][ w*512      ]);         \
    gload_lds16(bsrc + (size_t)(KS)*4096+2048, &Bs[BUF][2048 + w*512]);         \
}while(0)

    DMA2(0,0);
    DMA2(1,1);

    int c0 = 0, c1 = 1, c2 = 2;
    for (int k=0;k<NK2;k++){
        asm volatile("s_waitcnt vmcnt(4)" ::: "memory");
        __builtin_amdgcn_s_barrier();
        int ks = k+2; if (ks > NK2-1) ks = NK2-1;
        DMA2(c2, ks);
        const unsigned short* Ak = As[c0];
        const unsigned short* Bk = Bs[c0];
        bh8 a0 = *(const bh8*)(Ak + (wr*64      + l15)*32 + kb*8);
        bh8 a1 = *(const bh8*)(Ak + (wr*64 + 16 + l15)*32 + kb*8);
        bh8 a2 = *(const bh8*)(Ak + (wr*64 + 32 + l15)*32 + kb*8);
        bh8 a3 = *(const bh8*)(Ak + (wr*64 + 48 + l15)*32 + kb*8);
#pragma unroll
        for (int ni=0;ni<4;ni++){
            const int br = wc*64 + ni*16 + l15;
            bh8 b = *(const bh8*)(Bk + br*32 + kb*8);
            acc[0][ni]=MFMA16(a0,b,acc[0][ni]);
            acc[1][ni]=MFMA16(a1,b,acc[1][ni]);
            acc[2][ni]=MFMA16(a2,b,acc[2][ni]);
            acc[3][ni]=MFMA16(a3,b,acc[3][ni]);
        }
        int tmp = c0; c0 = c1; c1 = c2; c2 = tmp;
    }
    asm volatile("s_waitcnt vmcnt(0)" ::: "memory");

#pragma unroll
    for (int mi=0;mi<4;mi++){
#pragma unroll
        for (int qq=0;qq<4;qq++){
            int row = wr*64 + mi*16 + kb*4 + qq;
            if (row < rows){
                float* orow = out + (size_t)s_tok[row]*HIDDEN + n0 + wc*64 + l15;
#pragma unroll
                for (int ni=0;ni<4;ni++)
                    atomicAdd(orow + ni*16, acc[mi][ni][qq]);
            }
        }
    }
#undef DMA2
}

/* ---------------- host launch ---------------- */
extern "C" void kernel_launch(void* const* d_in, const int* in_sizes, int n_in,
                              void* d_out, int out_size, void* d_ws, size_t ws_size,
                              hipStream_t stream){
    const float* x    = (const float*)d_in[0];
    const float* gate = (const float*)d_in[1];
    const float* gup  = (const float*)d_in[2];
    const float* down = (const float*)d_in[3];
    float* out = (float*)d_out;
    char*  ws  = (char*)d_ws;

    int*   topk_id  = (int*)  (ws + 0x00000);
    float* topk_w   = (float*)(ws + 0x08000);
    int*   counts   = (int*)  (ws + 0x10000);
    int*   cursors  = (int*)  (ws + 0x10080);
    int*   offs     = (int*)  (ws + 0x10100);
    int*   nmt      = (int*)  (ws + 0x10180);
    int*   te       = (int*)  (ws + 0x10200);
    int*   tr0      = (int*)  (ws + 0x10400);
    int*   trn      = (int*)  (ws + 0x10600);
    int*   pair_tok = (int*)  (ws + 0x10800);
    float* pair_w   = (float*)(ws + 0x18800);
    unsigned short* gated = (unsigned short*)(ws + 0x21000);     // 8320*768*2 = 12.8MB
    unsigned short* xb    = (unsigned short*)(ws + 0xC60000);    // 8MB
    unsigned short* wT1   = (unsigned short*)(ws + 0x1460000);   // 32*12*64*8KB = 201.3MB
    unsigned short* wT2   = (unsigned short*)(ws + 0xD460000);   // 32*16*24*8KB = 100.7MB

    hipMemsetAsync(d_out, 0, (size_t)out_size*sizeof(float), stream);
    hipMemsetAsync(counts, 0, NEXPERT*sizeof(int), stream);

    cvt_x_k  <<<T_TOKENS*HIDDEN/(256*8), 256, 0, stream>>>(x, xb);
    router_k <<<T_TOKENS, 64, 0, stream>>>(x, gate, topk_id, topk_w, counts);
    sched_k  <<<1, 64, 0, stream>>>(counts, offs, cursors, nmt, te, tr0, trn);
    scatter_k<<<NPAIRS/256, 256, 0, stream>>>(topk_id, topk_w, cursors, pair_tok, pair_w);

    wt1_k    <<<NEXPERT*NT1*NK1, 256, 0, stream>>>(gup,  wT1);   // 24576 blocks
    wt2_k    <<<NEXPERT*NT2*NK2, 256, 0, stream>>>(down, wT2);   // 12288 blocks

    gemm1_k  <<<MT_MAX*NT1, 256, 0, stream>>>(xb, wT1, nmt, te, tr0, trn, pair_tok, pair_w, gated);
    gemm2_k  <<<MT_MAX*NT2, 256, 0, stream>>>(gated, wT2, nmt, te, tr0, trn, pair_tok, out);
}